// Round 1
// baseline (1895.566 us; speedup 1.0000x reference)
//
#include <hip/hip_runtime.h>
#include <math.h>

#define RR 2
#define CHN 2
#define RC 4            // RR*CHN
#define NN 20000
#define EE 100000
#define CC 256
#define EDM 16
#define MTOT (RC * NN)  // 80000

// GEMM tile config: block = 256 threads, tile = 64 rows x 256 cols, BK=32,
// thread tile 8x8 (64 fp32 accumulators).
#define BM 64
#define BK 32
#define LDA_PAD 68      // As leading dim (BM+4) to break staging bank conflicts

// ---------------------------------------------------------------------------
// x_l = x @ lin_W + lin_b    (80000x256) @ (256x256)
// ---------------------------------------------------------------------------
__global__ __launch_bounds__(256) void k_gemm_xl(const float* __restrict__ A,
                                                 const float* __restrict__ B,
                                                 const float* __restrict__ bias,
                                                 float* __restrict__ C) {
    __shared__ float As[BK * LDA_PAD];   // transposed: As[k][r]
    __shared__ float Bs[BK * CC];        // Bs[k][c]
    const int tid = threadIdx.x;
    const int i0  = blockIdx.x * BM;
    const int tc  = tid & 31;            // col group
    const int tr  = tid >> 5;            // row group
    const int r0  = tr * 8;
    const int c0  = tc * 8;

    float acc[8][8];
#pragma unroll
    for (int i = 0; i < 8; i++)
#pragma unroll
        for (int j = 0; j < 8; j++) acc[i][j] = 0.0f;

    for (int kc = 0; kc < CC; kc += BK) {
        __syncthreads();
        // stage A chunk (64 rows x 32 k), transposed into As
#pragma unroll
        for (int it = 0; it < 2; it++) {
            int q  = tid + it * 256;        // 0..511 float4 slots
            int r  = q >> 3;
            int k4 = (q & 7) << 2;
            float4 v = *(const float4*)(A + (size_t)(i0 + r) * CC + kc + k4);
            As[(k4 + 0) * LDA_PAD + r] = v.x;
            As[(k4 + 1) * LDA_PAD + r] = v.y;
            As[(k4 + 2) * LDA_PAD + r] = v.z;
            As[(k4 + 3) * LDA_PAD + r] = v.w;
        }
        // stage B chunk (32 k x 256 cols)
#pragma unroll
        for (int it = 0; it < 8; it++) {
            int q  = tid + it * 256;        // 0..2047 float4 slots
            int kk = q >> 6;
            int c4 = (q & 63) << 2;
            *(float4*)(Bs + kk * CC + c4) =
                *(const float4*)(B + (size_t)(kc + kk) * CC + c4);
        }
        __syncthreads();
#pragma unroll
        for (int kk = 0; kk < BK; kk++) {
            float a[8], b[8];
            *(float4*)(a)     = *(const float4*)(As + kk * LDA_PAD + r0);
            *(float4*)(a + 4) = *(const float4*)(As + kk * LDA_PAD + r0 + 4);
            *(float4*)(b)     = *(const float4*)(Bs + kk * CC + c0);
            *(float4*)(b + 4) = *(const float4*)(Bs + kk * CC + c0 + 4);
#pragma unroll
            for (int i = 0; i < 8; i++)
#pragma unroll
                for (int j = 0; j < 8; j++) acc[i][j] += a[i] * b[j];
        }
    }
#pragma unroll
    for (int i = 0; i < 8; i++) {
        size_t row = (size_t)(i0 + r0 + i) * CC;
#pragma unroll
        for (int j = 0; j < 8; j += 4) {
            float4 v;
            v.x = acc[i][j + 0] + bias[c0 + j + 0];
            v.y = acc[i][j + 1] + bias[c0 + j + 1];
            v.z = acc[i][j + 2] + bias[c0 + j + 2];
            v.w = acc[i][j + 3] + bias[c0 + j + 3];
            *(float4*)(C + row + c0 + j) = v;
        }
    }
}

// ---------------------------------------------------------------------------
// per-dst edge count
// ---------------------------------------------------------------------------
__global__ void k_count(const int* __restrict__ eidx, float* __restrict__ cnt) {
    int e = blockIdx.x * 256 + threadIdx.x;
    if (e < EE) atomicAdd(cnt + eidx[EE + e], 1.0f);
}

// ---------------------------------------------------------------------------
// message: per (rc, e): gelu(x_l[rc,src] + bond(edge_attr[e])) * w  -> atomic
// scatter into sums[rc,dst].  One wave per (rc,e); lane handles 4 channels.
// ---------------------------------------------------------------------------
__global__ __launch_bounds__(256) void k_msg(const float* __restrict__ x_l,
                                             const float* __restrict__ edge_attr,
                                             const float* __restrict__ ew,
                                             const float* __restrict__ bond_W,
                                             const float* __restrict__ bond_b,
                                             const int* __restrict__ eidx,
                                             float* __restrict__ sums) {
    const int lane = threadIdx.x & 63;
    const int wave = threadIdx.x >> 6;
    const int e    = blockIdx.x * 4 + wave;
    const int rc   = blockIdx.y;

    const int src = eidx[e];
    const int dst = eidx[EE + e];
    const float w = ew[(size_t)rc * EE + e];
    const int c0  = lane << 2;

    float4 bb = *(const float4*)(bond_b + c0);
    float a0 = bb.x, a1 = bb.y, a2 = bb.z, a3 = bb.w;
    const float* ea = edge_attr + (size_t)e * EDM;
#pragma unroll
    for (int k = 0; k < EDM; k++) {
        float av  = ea[k];  // wave-uniform, L1 broadcast
        float4 wv = *(const float4*)(bond_W + k * CC + c0);
        a0 += av * wv.x;
        a1 += av * wv.y;
        a2 += av * wv.z;
        a3 += av * wv.w;
    }
    float4 xl = *(const float4*)(x_l + ((size_t)rc * NN + src) * CC + c0);
    float v0 = xl.x + a0, v1 = xl.y + a1, v2 = xl.z + a2, v3 = xl.w + a3;
    const float is2 = 0.70710678118654752f;
    float m0 = 0.5f * v0 * (1.0f + erff(v0 * is2)) * w;
    float m1 = 0.5f * v1 * (1.0f + erff(v1 * is2)) * w;
    float m2 = 0.5f * v2 * (1.0f + erff(v2 * is2)) * w;
    float m3 = 0.5f * v3 * (1.0f + erff(v3 * is2)) * w;
    float* srow = sums + ((size_t)rc * NN + dst) * CC + c0;
    atomicAdd(srow + 0, m0);
    atomicAdd(srow + 1, m1);
    atomicAdd(srow + 2, m2);
    atomicAdd(srow + 3, m3);
}

// ---------------------------------------------------------------------------
// out = (sums * inv_cnt) @ linl_W + linl_b + x @ linr_W     (in-place on sums)
// Each block owns 64 full rows -> no cross-block read/write hazard.
// ---------------------------------------------------------------------------
__global__ __launch_bounds__(256) void k_final(float* __restrict__ OutSums,
                                               const float* __restrict__ X,
                                               const float* __restrict__ Wl,
                                               const float* __restrict__ bl,
                                               const float* __restrict__ Wr,
                                               const float* __restrict__ cnt) {
    __shared__ float As[BK * LDA_PAD];
    __shared__ float Bs[BK * CC];
    __shared__ float icnt[BM];
    const int tid = threadIdx.x;
    const int i0  = blockIdx.x * BM;
    const int tc  = tid & 31;
    const int tr  = tid >> 5;
    const int r0  = tr * 8;
    const int c0  = tc * 8;

    if (tid < BM) {
        int n = (i0 + tid) % NN;
        icnt[tid] = 1.0f / fmaxf(cnt[n], 1.0f);
    }

    float acc[8][8];
#pragma unroll
    for (int i = 0; i < 8; i++)
#pragma unroll
        for (int j = 0; j < 8; j++) acc[i][j] = 0.0f;

    // pass 1: mean @ linl_W ; pass 2: x @ linr_W
    for (int pass = 0; pass < 2; pass++) {
        const float* A = (pass == 0) ? OutSums : X;
        const float* B = (pass == 0) ? Wl : Wr;
        for (int kc = 0; kc < CC; kc += BK) {
            __syncthreads();
#pragma unroll
            for (int it = 0; it < 2; it++) {
                int q  = tid + it * 256;
                int r  = q >> 3;
                int k4 = (q & 7) << 2;
                float4 v = *(const float4*)(A + (size_t)(i0 + r) * CC + kc + k4);
                float s = (pass == 0) ? icnt[r] : 1.0f;
                As[(k4 + 0) * LDA_PAD + r] = v.x * s;
                As[(k4 + 1) * LDA_PAD + r] = v.y * s;
                As[(k4 + 2) * LDA_PAD + r] = v.z * s;
                As[(k4 + 3) * LDA_PAD + r] = v.w * s;
            }
#pragma unroll
            for (int it = 0; it < 8; it++) {
                int q  = tid + it * 256;
                int kk = q >> 6;
                int c4 = (q & 63) << 2;
                *(float4*)(Bs + kk * CC + c4) =
                    *(const float4*)(B + (size_t)(kc + kk) * CC + c4);
            }
            __syncthreads();
#pragma unroll
            for (int kk = 0; kk < BK; kk++) {
                float a[8], b[8];
                *(float4*)(a)     = *(const float4*)(As + kk * LDA_PAD + r0);
                *(float4*)(a + 4) = *(const float4*)(As + kk * LDA_PAD + r0 + 4);
                *(float4*)(b)     = *(const float4*)(Bs + kk * CC + c0);
                *(float4*)(b + 4) = *(const float4*)(Bs + kk * CC + c0 + 4);
#pragma unroll
                for (int i = 0; i < 8; i++)
#pragma unroll
                    for (int j = 0; j < 8; j++) acc[i][j] += a[i] * b[j];
            }
        }
    }
    // epilogue: all reads of OutSums rows [i0,i0+64) are complete (barrier-
    // ordered within this block; no other block touches these rows).
#pragma unroll
    for (int i = 0; i < 8; i++) {
        size_t row = (size_t)(i0 + r0 + i) * CC;
#pragma unroll
        for (int j = 0; j < 8; j += 4) {
            float4 v;
            v.x = acc[i][j + 0] + bl[c0 + j + 0];
            v.y = acc[i][j + 1] + bl[c0 + j + 1];
            v.z = acc[i][j + 2] + bl[c0 + j + 2];
            v.w = acc[i][j + 3] + bl[c0 + j + 3];
            *(float4*)(OutSums + row + c0 + j) = v;
        }
    }
}

extern "C" void kernel_launch(void* const* d_in, const int* in_sizes, int n_in,
                              void* d_out, int out_size, void* d_ws, size_t ws_size,
                              hipStream_t stream) {
    (void)in_sizes; (void)n_in; (void)out_size; (void)ws_size;
    const float* x           = (const float*)d_in[0];
    const float* edge_attr   = (const float*)d_in[1];
    const float* edge_weight = (const float*)d_in[2];
    const float* lin_W       = (const float*)d_in[3];
    const float* lin_b       = (const float*)d_in[4];
    const float* linl_W      = (const float*)d_in[5];
    const float* linl_b      = (const float*)d_in[6];
    const float* linr_W      = (const float*)d_in[7];
    const float* bond_W      = (const float*)d_in[8];
    const float* bond_b      = (const float*)d_in[9];
    const int*   edge_index  = (const int*)d_in[10];

    float* x_l  = (float*)d_ws;                       // 80000*256 fp32
    float* cnt  = x_l + (size_t)MTOT * CC;            // 20000 fp32
    float* sums = (float*)d_out;                      // sums -> out, in place

    hipMemsetAsync(d_out, 0, (size_t)MTOT * CC * sizeof(float), stream);
    hipMemsetAsync(cnt, 0, NN * sizeof(float), stream);

    k_gemm_xl<<<MTOT / BM, 256, 0, stream>>>(x, lin_W, lin_b, x_l);
    k_count<<<(EE + 255) / 256, 256, 0, stream>>>(edge_index, cnt);
    k_msg<<<dim3(EE / 4, RC), 256, 0, stream>>>(x_l, edge_attr, edge_weight,
                                                bond_W, bond_b, edge_index, sums);
    k_final<<<MTOT / BM, 256, 0, stream>>>(sums, x, linl_W, linl_b, linr_W, cnt);
}

// Round 2
// 742.370 us; speedup vs baseline: 2.5534x; 2.5534x over previous
//
#include <hip/hip_runtime.h>
#include <math.h>

#define RR 2
#define CHN 2
#define RC 4            // RR*CHN
#define NN 20000
#define EE 100000
#define CC 256
#define EDM 16
#define MTOT (RC * NN)  // 80000

// GEMM tile config: block = 256 threads, tile = 64 rows x 256 cols, BK=32,
// thread tile 8x8 (64 fp32 accumulators).
#define BM 64
#define BK 32
#define LDA_PAD 68      // As leading dim to break staging bank conflicts

// ---------------------------------------------------------------------------
// x_l = x @ lin_W + lin_b    (80000x256) @ (256x256)
// ---------------------------------------------------------------------------
__global__ __launch_bounds__(256) void k_gemm_xl(const float* __restrict__ A,
                                                 const float* __restrict__ B,
                                                 const float* __restrict__ bias,
                                                 float* __restrict__ C) {
    __shared__ float As[BK * LDA_PAD];   // transposed: As[k][r]
    __shared__ float Bs[BK * CC];        // Bs[k][c]
    const int tid = threadIdx.x;
    const int i0  = blockIdx.x * BM;
    const int tc  = tid & 31;            // col group
    const int tr  = tid >> 5;            // row group
    const int r0  = tr * 8;
    const int c0  = tc * 8;

    float acc[8][8];
#pragma unroll
    for (int i = 0; i < 8; i++)
#pragma unroll
        for (int j = 0; j < 8; j++) acc[i][j] = 0.0f;

    for (int kc = 0; kc < CC; kc += BK) {
        __syncthreads();
#pragma unroll
        for (int it = 0; it < 2; it++) {
            int q  = tid + it * 256;
            int r  = q >> 3;
            int k4 = (q & 7) << 2;
            float4 v = *(const float4*)(A + (size_t)(i0 + r) * CC + kc + k4);
            As[(k4 + 0) * LDA_PAD + r] = v.x;
            As[(k4 + 1) * LDA_PAD + r] = v.y;
            As[(k4 + 2) * LDA_PAD + r] = v.z;
            As[(k4 + 3) * LDA_PAD + r] = v.w;
        }
#pragma unroll
        for (int it = 0; it < 8; it++) {
            int q  = tid + it * 256;
            int kk = q >> 6;
            int c4 = (q & 63) << 2;
            *(float4*)(Bs + kk * CC + c4) =
                *(const float4*)(B + (size_t)(kc + kk) * CC + c4);
        }
        __syncthreads();
#pragma unroll
        for (int kk = 0; kk < BK; kk++) {
            float a[8], b[8];
            *(float4*)(a)     = *(const float4*)(As + kk * LDA_PAD + r0);
            *(float4*)(a + 4) = *(const float4*)(As + kk * LDA_PAD + r0 + 4);
            *(float4*)(b)     = *(const float4*)(Bs + kk * CC + c0);
            *(float4*)(b + 4) = *(const float4*)(Bs + kk * CC + c0 + 4);
#pragma unroll
            for (int i = 0; i < 8; i++)
#pragma unroll
                for (int j = 0; j < 8; j++) acc[i][j] += a[i] * b[j];
        }
    }
#pragma unroll
    for (int i = 0; i < 8; i++) {
        size_t row = (size_t)(i0 + r0 + i) * CC;
#pragma unroll
        for (int j = 0; j < 8; j += 4) {
            float4 v;
            v.x = acc[i][j + 0] + bias[c0 + j + 0];
            v.y = acc[i][j + 1] + bias[c0 + j + 1];
            v.z = acc[i][j + 2] + bias[c0 + j + 2];
            v.w = acc[i][j + 3] + bias[c0 + j + 3];
            *(float4*)(C + row + c0 + j) = v;
        }
    }
}

// ---------------------------------------------------------------------------
// CSR build: count -> scan -> scatter
// ---------------------------------------------------------------------------
__global__ void k_count(const int* __restrict__ eidx, int* __restrict__ cnt) {
    int e = blockIdx.x * 256 + threadIdx.x;
    if (e < EE) atomicAdd(cnt + eidx[EE + e], 1);
}

#define SCAN_T 1024
#define SCHUNK 20   // ceil(20000/1024)
__global__ __launch_bounds__(1024) void k_scan(const int* __restrict__ cnt,
                                               int* __restrict__ offs,
                                               int* __restrict__ cursor) {
    __shared__ int ps[SCAN_T];
    const int t = threadIdx.x;
    const int base = t * SCHUNK;
    int s = 0;
#pragma unroll
    for (int i = 0; i < SCHUNK; i++) {
        int idx = base + i;
        if (idx < NN) s += cnt[idx];
    }
    ps[t] = s;
    __syncthreads();
    for (int off = 1; off < SCAN_T; off <<= 1) {
        int v = (t >= off) ? ps[t - off] : 0;
        __syncthreads();
        ps[t] += v;
        __syncthreads();
    }
    int excl = (t == 0) ? 0 : ps[t - 1];
#pragma unroll
    for (int i = 0; i < SCHUNK; i++) {
        int idx = base + i;
        if (idx < NN) {
            offs[idx]   = excl;
            cursor[idx] = excl;
            excl += cnt[idx];
        }
    }
    if (t == SCAN_T - 1) offs[NN] = ps[SCAN_T - 1];
}

__global__ void k_scatter(const int* __restrict__ eidx, int* __restrict__ cursor,
                          int* __restrict__ bucket) {
    int e = blockIdx.x * 256 + threadIdx.x;
    if (e < EE) {
        int d = eidx[EE + e];
        int p = atomicAdd(cursor + d, 1);
        bucket[p] = e;
    }
}

// ---------------------------------------------------------------------------
// gather-sum: block = node n (4 waves = rc), lane = 4 channels.
// mean[rc,n,:] = (1/deg) * sum_{e: dst=n} gelu(x_l[rc,src]+bond(e)) * w[rc,e]
// Writes each output row exactly once -> zero fp atomics.
// ---------------------------------------------------------------------------
__global__ __launch_bounds__(256) void k_agg(const float* __restrict__ x_l,
                                             const float* __restrict__ edge_attr,
                                             const float* __restrict__ ew,
                                             const float* __restrict__ bond_W,
                                             const float* __restrict__ bond_b,
                                             const int* __restrict__ eidx,
                                             const int* __restrict__ offs,
                                             const int* __restrict__ bucket,
                                             float* __restrict__ mean_out) {
    const int n    = blockIdx.x;
    const int rc   = threadIdx.x >> 6;
    const int lane = threadIdx.x & 63;
    const int c0   = lane << 2;
    const int beg  = offs[n];
    const int end  = offs[n + 1];

    const float4 bb = *(const float4*)(bond_b + c0);
    float a0 = 0.0f, a1 = 0.0f, a2 = 0.0f, a3 = 0.0f;
    const float is2 = 0.70710678118654752f;

    for (int j = beg; j < end; j++) {
        const int e   = bucket[j];
        const int src = eidx[e];
        const float w = ew[(size_t)rc * EE + e];
        float e0 = bb.x, e1 = bb.y, e2 = bb.z, e3 = bb.w;
        const float* ea = edge_attr + (size_t)e * EDM;
#pragma unroll
        for (int k = 0; k < EDM; k++) {
            float av  = ea[k];                          // wave-uniform
            float4 wv = *(const float4*)(bond_W + k * CC + c0);  // L1-resident
            e0 += av * wv.x;
            e1 += av * wv.y;
            e2 += av * wv.z;
            e3 += av * wv.w;
        }
        float4 xl = *(const float4*)(x_l + ((size_t)rc * NN + src) * CC + c0);
        float v0 = xl.x + e0, v1 = xl.y + e1, v2 = xl.z + e2, v3 = xl.w + e3;
        a0 += 0.5f * v0 * (1.0f + erff(v0 * is2)) * w;
        a1 += 0.5f * v1 * (1.0f + erff(v1 * is2)) * w;
        a2 += 0.5f * v2 * (1.0f + erff(v2 * is2)) * w;
        a3 += 0.5f * v3 * (1.0f + erff(v3 * is2)) * w;
    }
    const float inv = 1.0f / fmaxf((float)(end - beg), 1.0f);
    float4 o;
    o.x = a0 * inv; o.y = a1 * inv; o.z = a2 * inv; o.w = a3 * inv;
    *(float4*)(mean_out + ((size_t)rc * NN + n) * CC + c0) = o;
}

// ---------------------------------------------------------------------------
// out = mean @ linl_W + linl_b + x @ linr_W     (in-place on mean/d_out)
// Each block owns 64 full rows -> no cross-block read/write hazard.
// ---------------------------------------------------------------------------
__global__ __launch_bounds__(256) void k_final(float* __restrict__ OutMean,
                                               const float* __restrict__ X,
                                               const float* __restrict__ Wl,
                                               const float* __restrict__ bl,
                                               const float* __restrict__ Wr) {
    __shared__ float As[BK * LDA_PAD];
    __shared__ float Bs[BK * CC];
    const int tid = threadIdx.x;
    const int i0  = blockIdx.x * BM;
    const int tc  = tid & 31;
    const int tr  = tid >> 5;
    const int r0  = tr * 8;
    const int c0  = tc * 8;

    float acc[8][8];
#pragma unroll
    for (int i = 0; i < 8; i++)
#pragma unroll
        for (int j = 0; j < 8; j++) acc[i][j] = 0.0f;

    for (int pass = 0; pass < 2; pass++) {
        const float* A = (pass == 0) ? OutMean : X;
        const float* B = (pass == 0) ? Wl : Wr;
        for (int kc = 0; kc < CC; kc += BK) {
            __syncthreads();
#pragma unroll
            for (int it = 0; it < 2; it++) {
                int q  = tid + it * 256;
                int r  = q >> 3;
                int k4 = (q & 7) << 2;
                float4 v = *(const float4*)(A + (size_t)(i0 + r) * CC + kc + k4);
                As[(k4 + 0) * LDA_PAD + r] = v.x;
                As[(k4 + 1) * LDA_PAD + r] = v.y;
                As[(k4 + 2) * LDA_PAD + r] = v.z;
                As[(k4 + 3) * LDA_PAD + r] = v.w;
            }
#pragma unroll
            for (int it = 0; it < 8; it++) {
                int q  = tid + it * 256;
                int kk = q >> 6;
                int c4 = (q & 63) << 2;
                *(float4*)(Bs + kk * CC + c4) =
                    *(const float4*)(B + (size_t)(kc + kk) * CC + c4);
            }
            __syncthreads();
#pragma unroll
            for (int kk = 0; kk < BK; kk++) {
                float a[8], b[8];
                *(float4*)(a)     = *(const float4*)(As + kk * LDA_PAD + r0);
                *(float4*)(a + 4) = *(const float4*)(As + kk * LDA_PAD + r0 + 4);
                *(float4*)(b)     = *(const float4*)(Bs + kk * CC + c0);
                *(float4*)(b + 4) = *(const float4*)(Bs + kk * CC + c0 + 4);
#pragma unroll
                for (int i = 0; i < 8; i++)
#pragma unroll
                    for (int j = 0; j < 8; j++) acc[i][j] += a[i] * b[j];
            }
        }
    }
#pragma unroll
    for (int i = 0; i < 8; i++) {
        size_t row = (size_t)(i0 + r0 + i) * CC;
#pragma unroll
        for (int j = 0; j < 8; j += 4) {
            float4 v;
            v.x = acc[i][j + 0] + bl[c0 + j + 0];
            v.y = acc[i][j + 1] + bl[c0 + j + 1];
            v.z = acc[i][j + 2] + bl[c0 + j + 2];
            v.w = acc[i][j + 3] + bl[c0 + j + 3];
            *(float4*)(OutMean + row + c0 + j) = v;
        }
    }
}

extern "C" void kernel_launch(void* const* d_in, const int* in_sizes, int n_in,
                              void* d_out, int out_size, void* d_ws, size_t ws_size,
                              hipStream_t stream) {
    (void)in_sizes; (void)n_in; (void)out_size; (void)ws_size;
    const float* x           = (const float*)d_in[0];
    const float* edge_attr   = (const float*)d_in[1];
    const float* edge_weight = (const float*)d_in[2];
    const float* lin_W       = (const float*)d_in[3];
    const float* lin_b       = (const float*)d_in[4];
    const float* linl_W      = (const float*)d_in[5];
    const float* linl_b      = (const float*)d_in[6];
    const float* linr_W      = (const float*)d_in[7];
    const float* bond_W      = (const float*)d_in[8];
    const float* bond_b      = (const float*)d_in[9];
    const int*   edge_index  = (const int*)d_in[10];

    float* x_l    = (float*)d_ws;                        // 80000*256 fp32
    int*   cnt    = (int*)(x_l + (size_t)MTOT * CC);     // N
    int*   offs   = cnt + NN;                            // N+1
    int*   cursor = offs + NN + 1;                       // N
    int*   bucket = cursor + NN;                         // E
    float* mean   = (float*)d_out;                       // mean -> out, in place

    hipMemsetAsync(cnt, 0, NN * sizeof(int), stream);

    k_gemm_xl<<<MTOT / BM, 256, 0, stream>>>(x, lin_W, lin_b, x_l);
    k_count<<<(EE + 255) / 256, 256, 0, stream>>>(edge_index, cnt);
    k_scan<<<1, SCAN_T, 0, stream>>>(cnt, offs, cursor);
    k_scatter<<<(EE + 255) / 256, 256, 0, stream>>>(edge_index, cursor, bucket);
    k_agg<<<NN, 256, 0, stream>>>(x_l, edge_attr, edge_weight, bond_W, bond_b,
                                  edge_index, offs, bucket, mean);
    k_final<<<MTOT / BM, 256, 0, stream>>>(mean, x, linl_W, linl_b, linr_W);
}

// Round 3
// 389.159 us; speedup vs baseline: 4.8709x; 1.9076x over previous
//
#include <hip/hip_runtime.h>
#include <math.h>

#define NN 20000
#define EE 100000
#define CC 256
#define EDM 16
#define RC 4
#define MTOT (RC * NN)   // 80000

typedef __attribute__((ext_vector_type(8))) short short8;
typedef __attribute__((ext_vector_type(4))) float floatx4;

#define LDK 72   // LDS k-stride in bf16 (64 + 8 pad) -> 36 dwords, conflict-free b128

__device__ __forceinline__ unsigned short f2bf(float f) {
    union { float f; unsigned u; } v; v.f = f;
    unsigned r = v.u + 0x7FFF + ((v.u >> 16) & 1);   // RNE
    return (unsigned short)(r >> 16);
}
__device__ __forceinline__ float bf2f(unsigned short h) {
    union { unsigned u; float f; } v; v.u = ((unsigned)h) << 16;
    return v.f;
}

// ---------------------------------------------------------------------------
// Weight prep: transpose + bf16-convert.  linWT[n][k] = lin_W[k][n];
// WbT[n][0:256] = linl_W[:, n], WbT[n][256:512] = linr_W[:, n].
// ---------------------------------------------------------------------------
__global__ void k_prep(const float* __restrict__ lin_W,
                       const float* __restrict__ linl_W,
                       const float* __restrict__ linr_W,
                       unsigned short* __restrict__ linWT,
                       unsigned short* __restrict__ WbT) {
    const int n = blockIdx.x;    // 256
    const int t = threadIdx.x;   // 256
    linWT[n * CC + t]       = f2bf(lin_W[t * CC + n]);
    WbT[n * 512 + t]        = f2bf(linl_W[t * CC + n]);
    WbT[n * 512 + 256 + t]  = f2bf(linr_W[t * CC + n]);
}

// ---------------------------------------------------------------------------
// MFMA GEMM: C[M x 256] = concat_k(A1, A2)[M x KTOT] @ B[KTOT x 256] + bias
// A1 covers k<256 (fp32), A2 covers k>=256 (fp32). BT is [256][KTOT] bf16
// (pre-transposed). Block: 64 rows x 256 cols, 4 waves, each wave 64 cols.
// OUTBF16=1 -> bf16 store (x_l); else fp32 store (may alias A1 in-place:
// blocks own disjoint 64-row slabs, all A1 reads precede epilogue writes).
// ---------------------------------------------------------------------------
template <int KTOT, int OUTBF16>
__global__ __launch_bounds__(256) void k_mm(const float* __restrict__ A1,
                                            const float* __restrict__ A2,
                                            const unsigned short* __restrict__ BT,
                                            const float* __restrict__ bias,
                                            float* __restrict__ Cf,
                                            unsigned short* __restrict__ Cb) {
    __shared__ unsigned short As[64 * LDK];
    __shared__ unsigned short Bs[256 * LDK];
    const int tid  = threadIdx.x;
    const int lane = tid & 63;
    const int wave = tid >> 6;
    const int i0   = blockIdx.x * 64;
    const int l15  = lane & 15;
    const int q4   = lane >> 4;   // 0..3

    floatx4 acc[4][4];
#pragma unroll
    for (int mt = 0; mt < 4; mt++)
#pragma unroll
        for (int nt = 0; nt < 4; nt++) acc[mt][nt] = (floatx4)0.0f;

    for (int kc = 0; kc < KTOT; kc += 64) {
        __syncthreads();
        // stage A: 64 rows x 64 k, fp32 -> bf16 inline
        const float* Asrc = (kc < 256) ? A1 : A2;
        const int kco     = (kc < 256) ? kc : kc - 256;
#pragma unroll
        for (int it = 0; it < 2; it++) {
            int q = tid + it * 256;      // 0..511 chunk ids (8 bf16 each)
            int r = q >> 3;
            int c = q & 7;
            const float* src = Asrc + (size_t)(i0 + r) * CC + kco + c * 8;
            float4 v0 = *(const float4*)(src);
            float4 v1 = *(const float4*)(src + 4);
            uint4 p;
            p.x = (unsigned)f2bf(v0.x) | ((unsigned)f2bf(v0.y) << 16);
            p.y = (unsigned)f2bf(v0.z) | ((unsigned)f2bf(v0.w) << 16);
            p.z = (unsigned)f2bf(v1.x) | ((unsigned)f2bf(v1.y) << 16);
            p.w = (unsigned)f2bf(v1.z) | ((unsigned)f2bf(v1.w) << 16);
            *(uint4*)(As + r * LDK + c * 8) = p;
        }
        // stage B: 256 n-rows x 64 k (bf16 direct copy from BT)
#pragma unroll
        for (int it = 0; it < 8; it++) {
            int q = tid + it * 256;      // 0..2047
            int n = q >> 3;
            int c = q & 7;
            *(uint4*)(Bs + n * LDK + c * 8) =
                *(const uint4*)(BT + (size_t)n * KTOT + kc + c * 8);
        }
        __syncthreads();
#pragma unroll
        for (int kk = 0; kk < 64; kk += 32) {
            short8 a[4], b[4];
#pragma unroll
            for (int mt = 0; mt < 4; mt++)
                a[mt] = *(const short8*)(As + (mt * 16 + l15) * LDK + kk + q4 * 8);
#pragma unroll
            for (int nt = 0; nt < 4; nt++)
                b[nt] = *(const short8*)(Bs + (wave * 64 + nt * 16 + l15) * LDK + kk + q4 * 8);
#pragma unroll
            for (int mt = 0; mt < 4; mt++)
#pragma unroll
                for (int nt = 0; nt < 4; nt++)
                    acc[mt][nt] = __builtin_amdgcn_mfma_f32_16x16x32_bf16(
                        a[mt], b[nt], acc[mt][nt], 0, 0, 0);
        }
    }
    // epilogue: C/D layout col=lane&15, row=(lane>>4)*4+reg  [verified m89/m91]
#pragma unroll
    for (int nt = 0; nt < 4; nt++) {
        const int col = wave * 64 + nt * 16 + l15;
        const float bz = bias[col];
#pragma unroll
        for (int mt = 0; mt < 4; mt++) {
#pragma unroll
            for (int r = 0; r < 4; r++) {
                const int row = i0 + mt * 16 + q4 * 4 + r;
                const float v = acc[mt][nt][r] + bz;
                if (OUTBF16) Cb[(size_t)row * CC + col] = f2bf(v);
                else         Cf[(size_t)row * CC + col] = v;
            }
        }
    }
}

// ---------------------------------------------------------------------------
// CSR build: count -> scan -> scatter
// ---------------------------------------------------------------------------
__global__ void k_count(const int* __restrict__ eidx, int* __restrict__ cnt) {
    int e = blockIdx.x * 256 + threadIdx.x;
    if (e < EE) atomicAdd(cnt + eidx[EE + e], 1);
}

#define SCAN_T 1024
#define SCHUNK 20
__global__ __launch_bounds__(1024) void k_scan(const int* __restrict__ cnt,
                                               int* __restrict__ offs,
                                               int* __restrict__ cursor) {
    __shared__ int ps[SCAN_T];
    const int t = threadIdx.x;
    const int base = t * SCHUNK;
    int s = 0;
#pragma unroll
    for (int i = 0; i < SCHUNK; i++) {
        int idx = base + i;
        if (idx < NN) s += cnt[idx];
    }
    ps[t] = s;
    __syncthreads();
    for (int off = 1; off < SCAN_T; off <<= 1) {
        int v = (t >= off) ? ps[t - off] : 0;
        __syncthreads();
        ps[t] += v;
        __syncthreads();
    }
    int excl = (t == 0) ? 0 : ps[t - 1];
#pragma unroll
    for (int i = 0; i < SCHUNK; i++) {
        int idx = base + i;
        if (idx < NN) {
            offs[idx]   = excl;
            cursor[idx] = excl;
            excl += cnt[idx];
        }
    }
    if (t == SCAN_T - 1) offs[NN] = ps[SCAN_T - 1];
}

__global__ void k_scatter(const int* __restrict__ eidx, int* __restrict__ cursor,
                          int* __restrict__ bucket) {
    int e = blockIdx.x * 256 + threadIdx.x;
    if (e < EE) {
        int d = eidx[EE + e];
        int p = atomicAdd(cursor + d, 1);
        bucket[p] = e;
    }
}

// ---------------------------------------------------------------------------
// gather-mean: block = node, thread = channel, 4 rc accumulators per lane.
// edge_emb computed ONCE per (edge, channel), shared across the 4 rc.
// ---------------------------------------------------------------------------
__global__ __launch_bounds__(256) void k_agg(const unsigned short* __restrict__ xlb,
                                             const float* __restrict__ edge_attr,
                                             const float* __restrict__ ew,
                                             const float* __restrict__ bond_W,
                                             const float* __restrict__ bond_b,
                                             const int* __restrict__ eidx,
                                             const int* __restrict__ offs,
                                             const int* __restrict__ bucket,
                                             float* __restrict__ mean_out) {
    const int n = blockIdx.x;
    const int c = threadIdx.x;
    const int beg = offs[n], end = offs[n + 1];
    const float bb  = bond_b[c];
    const float is2 = 0.70710678118654752f;
    float a0 = 0.f, a1 = 0.f, a2 = 0.f, a3 = 0.f;

#pragma unroll 2
    for (int j = beg; j < end; j++) {
        const int e   = bucket[j];
        const int src = eidx[e];
        const float w0 = ew[e];
        const float w1 = ew[EE + e];
        const float w2 = ew[2 * EE + e];
        const float w3 = ew[3 * EE + e];
        float emb = bb;
        const float* ea = edge_attr + (size_t)e * EDM;
#pragma unroll
        for (int k = 0; k < EDM; k++)
            emb += ea[k] * bond_W[k * CC + c];   // ea[k] wave-uniform; bond_W L1
        const size_t sb = (size_t)src * CC + c;
        float v0 = bf2f(xlb[sb])                      + emb;
        float v1 = bf2f(xlb[sb + (size_t)NN * CC])     + emb;
        float v2 = bf2f(xlb[sb + (size_t)2 * NN * CC]) + emb;
        float v3 = bf2f(xlb[sb + (size_t)3 * NN * CC]) + emb;
        a0 += 0.5f * v0 * (1.0f + erff(v0 * is2)) * w0;
        a1 += 0.5f * v1 * (1.0f + erff(v1 * is2)) * w1;
        a2 += 0.5f * v2 * (1.0f + erff(v2 * is2)) * w2;
        a3 += 0.5f * v3 * (1.0f + erff(v3 * is2)) * w3;
    }
    const float inv = 1.0f / fmaxf((float)(end - beg), 1.0f);
    const size_t ob = (size_t)n * CC + c;
    mean_out[ob]                       = a0 * inv;
    mean_out[ob + (size_t)NN * CC]     = a1 * inv;
    mean_out[ob + (size_t)2 * NN * CC] = a2 * inv;
    mean_out[ob + (size_t)3 * NN * CC] = a3 * inv;
}

extern "C" void kernel_launch(void* const* d_in, const int* in_sizes, int n_in,
                              void* d_out, int out_size, void* d_ws, size_t ws_size,
                              hipStream_t stream) {
    (void)in_sizes; (void)n_in; (void)out_size; (void)ws_size;
    const float* x           = (const float*)d_in[0];
    const float* edge_attr   = (const float*)d_in[1];
    const float* edge_weight = (const float*)d_in[2];
    const float* lin_W       = (const float*)d_in[3];
    const float* lin_b       = (const float*)d_in[4];
    const float* linl_W      = (const float*)d_in[5];
    const float* linl_b      = (const float*)d_in[6];
    const float* linr_W      = (const float*)d_in[7];
    const float* bond_W      = (const float*)d_in[8];
    const float* bond_b      = (const float*)d_in[9];
    const int*   edge_index  = (const int*)d_in[10];

    unsigned short* xlb   = (unsigned short*)d_ws;          // 80000*256 bf16
    unsigned short* linWT = xlb + (size_t)MTOT * CC;        // 256*256 bf16
    unsigned short* WbT   = linWT + CC * CC;                // 256*512 bf16
    int* cnt    = (int*)(WbT + CC * 512);                   // N
    int* offs   = cnt + NN;                                 // N+1
    int* cursor = offs + NN + 1;                            // N
    int* bucket = cursor + NN;                              // E
    float* mean = (float*)d_out;                            // mean -> out, in place

    hipMemsetAsync(cnt, 0, NN * sizeof(int), stream);

    k_prep<<<CC, CC, 0, stream>>>(lin_W, linl_W, linr_W, linWT, WbT);
    // x_l(bf16) = x @ lin_W + lin_b
    k_mm<256, 1><<<MTOT / 64, 256, 0, stream>>>(x, x, linWT, lin_b, nullptr, xlb);
    k_count<<<(EE + 255) / 256, 256, 0, stream>>>(edge_index, cnt);
    k_scan<<<1, SCAN_T, 0, stream>>>(cnt, offs, cursor);
    k_scatter<<<(EE + 255) / 256, 256, 0, stream>>>(edge_index, cursor, bucket);
    k_agg<<<NN, 256, 0, stream>>>(xlb, edge_attr, edge_weight, bond_W, bond_b,
                                  edge_index, offs, bucket, mean);
    // out = mean @ linl_W + linl_b + x @ linr_W   (K=512 fused, in-place)
    k_mm<512, 0><<<MTOT / 64, 256, 0, stream>>>(mean, x, WbT, linl_b,
                                                (float*)d_out, nullptr);
}

// Round 4
// 356.814 us; speedup vs baseline: 5.3125x; 1.0906x over previous
//
#include <hip/hip_runtime.h>
#include <math.h>

#define NN 20000
#define EE 100000
#define CC 256
#define EDM 16
#define RC 4
#define MTOT (RC * NN)   // 80000

typedef __attribute__((ext_vector_type(8))) short short8;
typedef __attribute__((ext_vector_type(4))) float floatx4;

#define LDK 72   // LDS k-stride in bf16 (64 + 8 pad) -> 36 dwords, conflict-free b128

__device__ __forceinline__ unsigned short f2bf(float f) {
    union { float f; unsigned u; } v; v.f = f;
    unsigned r = v.u + 0x7FFF + ((v.u >> 16) & 1);   // RNE
    return (unsigned short)(r >> 16);
}
__device__ __forceinline__ float bf2f(unsigned short h) {
    union { unsigned u; float f; } v; v.u = ((unsigned)h) << 16;
    return v.f;
}

// GELU(exact-erf) via Abramowitz-Stegun 7.1.26 (|erf err| < 1.5e-7).
// gelu(v) = 0.5v(1+erf(v/sqrt2)) = 0.5v + 0.5|v|*erf(|v|/sqrt2)  (sign-free)
// ~11 VALU + rcp + exp2 vs ~80 for libdevice erff.
__device__ __forceinline__ float gelu_fast(float v) {
    const float ax = fabsf(v) * 0.70710678118654752f;
    const float t  = __builtin_amdgcn_rcpf(fmaf(0.3275911f, ax, 1.0f));
    const float p  = t * fmaf(t, fmaf(t, fmaf(t, fmaf(t, 1.061405429f,
                                -1.453152027f), 1.421413741f), -0.284496736f),
                              0.254829592f);
    const float e  = __builtin_amdgcn_exp2f(ax * ax * -1.4426950408889634f);
    const float erf_ax = fmaf(-p, e, 1.0f);
    return fmaf(0.5f * fabsf(v), erf_ax, 0.5f * v);
}

// ---------------------------------------------------------------------------
// fused prep (weight transpose+bf16) + per-dst edge count
// blocks [0,256): prep row n.  blocks [256, 256+391): count edges.
// ---------------------------------------------------------------------------
__global__ void k_prep_count(const float* __restrict__ lin_W,
                             const float* __restrict__ linl_W,
                             const float* __restrict__ linr_W,
                             unsigned short* __restrict__ linWT,
                             unsigned short* __restrict__ WbT,
                             const int* __restrict__ eidx,
                             int* __restrict__ cnt) {
    const int b = blockIdx.x;
    const int t = threadIdx.x;
    if (b < CC) {
        linWT[b * CC + t]      = f2bf(lin_W[t * CC + b]);
        WbT[b * 512 + t]       = f2bf(linl_W[t * CC + b]);
        WbT[b * 512 + 256 + t] = f2bf(linr_W[t * CC + b]);
    } else {
        int e = (b - CC) * 256 + t;
        if (e < EE) atomicAdd(cnt + eidx[EE + e], 1);
    }
}

// ---------------------------------------------------------------------------
// MFMA GEMM: C[M x 256] = concat_k(A1, A2)[M x KTOT] @ B[KTOT x 256] + bias
// ---------------------------------------------------------------------------
template <int KTOT, int OUTBF16>
__global__ __launch_bounds__(256) void k_mm(const float* __restrict__ A1,
                                            const float* __restrict__ A2,
                                            const unsigned short* __restrict__ BT,
                                            const float* __restrict__ bias,
                                            float* __restrict__ Cf,
                                            unsigned short* __restrict__ Cb) {
    __shared__ unsigned short As[64 * LDK];
    __shared__ unsigned short Bs[256 * LDK];
    const int tid  = threadIdx.x;
    const int lane = tid & 63;
    const int wave = tid >> 6;
    const int i0   = blockIdx.x * 64;
    const int l15  = lane & 15;
    const int q4   = lane >> 4;   // 0..3

    floatx4 acc[4][4];
#pragma unroll
    for (int mt = 0; mt < 4; mt++)
#pragma unroll
        for (int nt = 0; nt < 4; nt++) acc[mt][nt] = (floatx4)0.0f;

    for (int kc = 0; kc < KTOT; kc += 64) {
        __syncthreads();
        const float* Asrc = (kc < 256) ? A1 : A2;
        const int kco     = (kc < 256) ? kc : kc - 256;
#pragma unroll
        for (int it = 0; it < 2; it++) {
            int q = tid + it * 256;
            int r = q >> 3;
            int c = q & 7;
            const float* src = Asrc + (size_t)(i0 + r) * CC + kco + c * 8;
            float4 v0 = *(const float4*)(src);
            float4 v1 = *(const float4*)(src + 4);
            uint4 p;
            p.x = (unsigned)f2bf(v0.x) | ((unsigned)f2bf(v0.y) << 16);
            p.y = (unsigned)f2bf(v0.z) | ((unsigned)f2bf(v0.w) << 16);
            p.z = (unsigned)f2bf(v1.x) | ((unsigned)f2bf(v1.y) << 16);
            p.w = (unsigned)f2bf(v1.z) | ((unsigned)f2bf(v1.w) << 16);
            *(uint4*)(As + r * LDK + c * 8) = p;
        }
#pragma unroll
        for (int it = 0; it < 8; it++) {
            int q = tid + it * 256;
            int n = q >> 3;
            int c = q & 7;
            *(uint4*)(Bs + n * LDK + c * 8) =
                *(const uint4*)(BT + (size_t)n * KTOT + kc + c * 8);
        }
        __syncthreads();
#pragma unroll
        for (int kk = 0; kk < 64; kk += 32) {
            short8 a[4], b[4];
#pragma unroll
            for (int mt = 0; mt < 4; mt++)
                a[mt] = *(const short8*)(As + (mt * 16 + l15) * LDK + kk + q4 * 8);
#pragma unroll
            for (int nt = 0; nt < 4; nt++)
                b[nt] = *(const short8*)(Bs + (wave * 64 + nt * 16 + l15) * LDK + kk + q4 * 8);
#pragma unroll
            for (int mt = 0; mt < 4; mt++)
#pragma unroll
                for (int nt = 0; nt < 4; nt++)
                    acc[mt][nt] = __builtin_amdgcn_mfma_f32_16x16x32_bf16(
                        a[mt], b[nt], acc[mt][nt], 0, 0, 0);
        }
    }
    // C/D layout: col=lane&15, row=(lane>>4)*4+reg  [verified m89/m91]
#pragma unroll
    for (int nt = 0; nt < 4; nt++) {
        const int col = wave * 64 + nt * 16 + l15;
        const float bz = bias[col];
#pragma unroll
        for (int mt = 0; mt < 4; mt++) {
#pragma unroll
            for (int r = 0; r < 4; r++) {
                const int row = i0 + mt * 16 + q4 * 4 + r;
                const float v = acc[mt][nt][r] + bz;
                if (OUTBF16) Cb[(size_t)row * CC + col] = f2bf(v);
                else         Cf[(size_t)row * CC + col] = v;
            }
        }
    }
}

// ---------------------------------------------------------------------------
// CSR scan + scatter
// ---------------------------------------------------------------------------
#define SCAN_T 1024
#define SCHUNK 20
__global__ __launch_bounds__(1024) void k_scan(const int* __restrict__ cnt,
                                               int* __restrict__ offs,
                                               int* __restrict__ cursor) {
    __shared__ int ps[SCAN_T];
    const int t = threadIdx.x;
    const int base = t * SCHUNK;
    int s = 0;
#pragma unroll
    for (int i = 0; i < SCHUNK; i++) {
        int idx = base + i;
        if (idx < NN) s += cnt[idx];
    }
    ps[t] = s;
    __syncthreads();
    for (int off = 1; off < SCAN_T; off <<= 1) {
        int v = (t >= off) ? ps[t - off] : 0;
        __syncthreads();
        ps[t] += v;
        __syncthreads();
    }
    int excl = (t == 0) ? 0 : ps[t - 1];
#pragma unroll
    for (int i = 0; i < SCHUNK; i++) {
        int idx = base + i;
        if (idx < NN) {
            offs[idx]   = excl;
            cursor[idx] = excl;
            excl += cnt[idx];
        }
    }
    if (t == SCAN_T - 1) offs[NN] = ps[SCAN_T - 1];
}

__global__ void k_scatter(const int* __restrict__ eidx, int* __restrict__ cursor,
                          int* __restrict__ bucket) {
    int e = blockIdx.x * 256 + threadIdx.x;
    if (e < EE) {
        int d = eidx[EE + e];
        int p = atomicAdd(cursor + d, 1);
        bucket[p] = e;
    }
}

// ---------------------------------------------------------------------------
// gather-mean: block = node, thread = channel, 4 rc accumulators per lane.
// ---------------------------------------------------------------------------
__global__ __launch_bounds__(256) void k_agg(const unsigned short* __restrict__ xlb,
                                             const float* __restrict__ edge_attr,
                                             const float* __restrict__ ew,
                                             const float* __restrict__ bond_W,
                                             const float* __restrict__ bond_b,
                                             const int* __restrict__ eidx,
                                             const int* __restrict__ offs,
                                             const int* __restrict__ bucket,
                                             float* __restrict__ mean_out) {
    const int n = blockIdx.x;
    const int c = threadIdx.x;
    const int beg = offs[n], end = offs[n + 1];
    const float bb = bond_b[c];
    float a0 = 0.f, a1 = 0.f, a2 = 0.f, a3 = 0.f;

#pragma unroll 2
    for (int j = beg; j < end; j++) {
        const int e   = bucket[j];
        const int src = eidx[e];
        const float w0 = ew[e];
        const float w1 = ew[EE + e];
        const float w2 = ew[2 * EE + e];
        const float w3 = ew[3 * EE + e];
        float emb = bb;
        const float* ea = edge_attr + (size_t)e * EDM;
#pragma unroll
        for (int k = 0; k < EDM; k++)
            emb += ea[k] * bond_W[k * CC + c];   // ea[k] wave-uniform; bond_W L1
        const size_t sb = (size_t)src * CC + c;
        float v0 = bf2f(xlb[sb])                       + emb;
        float v1 = bf2f(xlb[sb + (size_t)NN * CC])     + emb;
        float v2 = bf2f(xlb[sb + (size_t)2 * NN * CC]) + emb;
        float v3 = bf2f(xlb[sb + (size_t)3 * NN * CC]) + emb;
        a0 += gelu_fast(v0) * w0;
        a1 += gelu_fast(v1) * w1;
        a2 += gelu_fast(v2) * w2;
        a3 += gelu_fast(v3) * w3;
    }
    const float inv = 1.0f / fmaxf((float)(end - beg), 1.0f);
    const size_t ob = (size_t)n * CC + c;
    mean_out[ob]                       = a0 * inv;
    mean_out[ob + (size_t)NN * CC]     = a1 * inv;
    mean_out[ob + (size_t)2 * NN * CC] = a2 * inv;
    mean_out[ob + (size_t)3 * NN * CC] = a3 * inv;
}

extern "C" void kernel_launch(void* const* d_in, const int* in_sizes, int n_in,
                              void* d_out, int out_size, void* d_ws, size_t ws_size,
                              hipStream_t stream) {
    (void)in_sizes; (void)n_in; (void)out_size; (void)ws_size;
    const float* x           = (const float*)d_in[0];
    const float* edge_attr   = (const float*)d_in[1];
    const float* edge_weight = (const float*)d_in[2];
    const float* lin_W       = (const float*)d_in[3];
    const float* lin_b       = (const float*)d_in[4];
    const float* linl_W      = (const float*)d_in[5];
    const float* linl_b      = (const float*)d_in[6];
    const float* linr_W      = (const float*)d_in[7];
    const float* bond_W      = (const float*)d_in[8];
    const float* bond_b      = (const float*)d_in[9];
    const int*   edge_index  = (const int*)d_in[10];

    unsigned short* xlb   = (unsigned short*)d_ws;          // 80000*256 bf16
    unsigned short* linWT = xlb + (size_t)MTOT * CC;        // 256*256 bf16
    unsigned short* WbT   = linWT + CC * CC;                // 256*512 bf16
    int* cnt    = (int*)(WbT + CC * 512);                   // N
    int* offs   = cnt + NN;                                 // N+1
    int* cursor = offs + NN + 1;                            // N
    int* bucket = cursor + NN;                              // E
    float* mean = (float*)d_out;                            // mean -> out, in place

    hipMemsetAsync(cnt, 0, NN * sizeof(int), stream);

    k_prep_count<<<CC + (EE + 255) / 256, 256, 0, stream>>>(
        lin_W, linl_W, linr_W, linWT, WbT, edge_index, cnt);
    // x_l(bf16) = x @ lin_W + lin_b
    k_mm<256, 1><<<MTOT / 64, 256, 0, stream>>>(x, x, linWT, lin_b, nullptr, xlb);
    k_scan<<<1, SCAN_T, 0, stream>>>(cnt, offs, cursor);
    k_scatter<<<(EE + 255) / 256, 256, 0, stream>>>(edge_index, cursor, bucket);
    k_agg<<<NN, 256, 0, stream>>>(xlb, edge_attr, edge_weight, bond_W, bond_b,
                                  edge_index, offs, bucket, mean);
    // out = mean @ linl_W + linl_b + x @ linr_W   (K=512 fused, in-place)
    k_mm<512, 0><<<MTOT / 64, 256, 0, stream>>>(mean, x, WbT, linl_b,
                                                (float*)d_out, nullptr);
}